// Round 13
// baseline (784.673 us; speedup 1.0000x reference)
//
#include <hip/hip_runtime.h>

// LinearAttention: b=16, n=4096, dim=512, H=8, D=64, inner=512. T=65536 tokens.
// I/O dtype: fp32 (per reference). Compute: bf16 MFMA, fp32 accumulate.
//
// Algebraic form: out[t] = sum_h z_h(t) * (q'_h[t] @ kv_h) @ Wout_h
//                        = (z .* q') @ Pcat,  Pcat_b[c][h*64+d] = sum_e kv_h[d][e] Wout[c][h*64+e]
// z applied to the fp32 accumulator of gemm_final (den via broadcast-B MFMA)
// — R12 proved this fusion is net-positive vs a standalone apply_z pass.
//
// ws layout (~139 MiB):
//   wq_bf  [1536x512 bf16]  W_qkv converted + ROW-PERMUTED (q | per-head k|v)
//   wo_bf  [ 512x512 bf16]  converted W_out
//   wsq    [65536x512 bf16] q' = act(x@Wq^T)  (UNscaled; z applied in gemm_final)
//   xb     [65536x512 bf16] x converted once; REUSED as P after gemm_qkv
//   kvglob [128 x 64x80 f32] kv accumulator (atomicAdd), col e=64 = ksum
//   ksum_bf[16 x 512 bf16]  per-batch concatenated k-sum (h*64+d)
//
// R11->R13 (R12's revert regressed; R11 restored): the ONLY change vs R11 is
// full unroll of both GEMM K-loops with static cur = t&1 — all LDS fragment
// addresses (row*64 + swizzle XOR) and staging offsets become compile-time
// constants, killing the VALU address math that co-dominated (VALUBusy 35% >=
// MfmaUtil 34%). Sync structure byte-identical, just unrolled.

typedef unsigned short u16;
typedef u16 u16x4 __attribute__((ext_vector_type(4)));
typedef u16 u16x8 __attribute__((ext_vector_type(8)));
typedef __bf16 bf16x8 __attribute__((ext_vector_type(8)));
typedef float f32x4 __attribute__((ext_vector_type(4)));

__device__ __forceinline__ float bf2f(u16 x) {
    union { unsigned u; float f; } t; t.u = ((unsigned)x) << 16; return t.f;
}
__device__ __forceinline__ u16 f2bf(float f) {
    union { float f; unsigned u; } t; t.f = f;
    unsigned r = t.u + 0x7fffu + ((t.u >> 16) & 1u);   // RNE
    return (u16)(r >> 16);
}
__device__ __forceinline__ float act_fn(float v) {     // 1 + elu
    return v > 0.0f ? v + 1.0f : __expf(v);
}
__device__ __forceinline__ void cvt8(const float* __restrict__ s, u16* __restrict__ d) {
    f32x4 lo = *(const f32x4*)s;
    f32x4 hi = *(const f32x4*)(s + 4);
    u16x8 o = { f2bf(lo[0]), f2bf(lo[1]), f2bf(lo[2]), f2bf(lo[3]),
                f2bf(hi[0]), f2bf(hi[1]), f2bf(hi[2]), f2bf(hi[3]) };
    *(u16x8*)d = o;
}
// async global->LDS, 16B per lane. LDS dest = wave-uniform base + lane*16.
__device__ __forceinline__ void gld16(const u16* g, u16* l) {
    __builtin_amdgcn_global_load_lds(
        (__attribute__((address_space(1))) const void*)g,
        (__attribute__((address_space(3))) void*)l, 16, 0, 0);
}

// ---------------------------------------------------------------------------
// convert_all: x (4,194,304 x8 units) -> xb ; W_qkv (98,304 units) -> wq_bf
// with the head-interleaved row permutation ; W_out (32,768) -> wo_bf ;
// zero kvglob (81,920 f32 = 10,240 x8 units). 17,216 x 256 exact.
// ---------------------------------------------------------------------------
__global__ __launch_bounds__(256) void convert_all(const float* __restrict__ x,
                                                   const float* __restrict__ Wqkv,
                                                   const float* __restrict__ Wout,
                                                   u16* __restrict__ xb,
                                                   u16* __restrict__ wq,
                                                   u16* __restrict__ wo,
                                                   float* __restrict__ kvg)
{
    size_t u = (size_t)blockIdx.x * 256 + threadIdx.x;
    if (u < 4194304ull) {
        cvt8(x + u * 8, xb + u * 8);
    } else if (u < 4292608ull) {
        u -= 4194304ull;                       // dest unit within wq_bf
        const int drow = (int)(u >> 6);
        int srow;
        if (drow < 512) srow = drow;
        else {
            const int t = drow - 512, h = t >> 7, j = t & 127;
            srow = (j < 64) ? (512 + h * 64 + j) : (1024 + h * 64 + (j - 64));
        }
        cvt8(Wqkv + (size_t)srow * 512 + (u & 63) * 8, wq + u * 8);
    } else if (u < 4325376ull) {
        u -= 4292608ull; cvt8(Wout + u * 8, wo + u * 8);
    } else {
        u -= 4325376ull;
        f32x4 z = { 0.f, 0.f, 0.f, 0.f };
        *(f32x4*)&kvg[u * 8] = z;
        *(f32x4*)&kvg[u * 8 + 4] = z;
    }
}

// ---------------------------------------------------------------------------
// gemm_qkv: C128x128 tile of x @ Wqkv_perm^T, K=512, 8 K-steps of BK=64.
// 2-phase __syncthreads double-buffer (proven), 512 thr / 8 waves; wave owns
// 32x64 (acc 2x4). T2 swizzle both-sides; T1 XCD remap (bijective, cpx=768).
// K-loop FULLY UNROLLED, cur = t&1 static -> all LDS addrs are immediates.
// Col-tiles 0..3 -> q: act + store to wsq.  Col-tiles 4..11 -> head h=nt-4:
// kv epilogue (KT/VT overlay; last compute reads buf1 -> disjoint).
// ---------------------------------------------------------------------------
__global__ __launch_bounds__(512, 4) void gemm_qkv(const u16* __restrict__ A,
                                                   const u16* __restrict__ Bw,
                                                   u16* __restrict__ Cq,
                                                   float* __restrict__ kvglob)
{
    __shared__ u16 SMF[32768];     // 64 KB: buf b at b*16384 (As 8192 | Bs 8192)
    const int id = blockIdx.y * 12 + blockIdx.x;        // linear dispatch id
    const int o  = (id & 7) * 768 + (id >> 3);          // T1 bijective remap
    const int nt = o % 12;         // col-tile (fastest within XCD chunk)
    const int mt = o / 12;         // M-tile
    const size_t row0 = (size_t)mt * 128;
    const int col0 = nt * 128;
    const int tid = threadIdx.x, wave = tid >> 6, lane = tid & 63;
    const int frow = lane & 15, quad = lane >> 4;
    const int wr = (wave >> 1) * 32, wc = (wave & 1) * 64;

    f32x4 acc[2][4] = {};

    // staging chunks (16B each): ch in [0,1024) covers 128x64; row = ch>>3;
    // LDS linear at u16 ch*8; SOURCE col16 = (ch&7)^(row&7)  [T2 involution]
    const int ch0 = wave * 64 + lane, ch1 = 512 + ch0;
    const int ar0 = ch0 >> 3, ac0 = ((ch0 & 7) ^ (ar0 & 7)) * 8;
    const int ar1 = ch1 >> 3, ac1 = ((ch1 & 7) ^ (ar1 & 7)) * 8;
    const u16* gA0 = A + (row0 + ar0) * 512 + ac0;
    const u16* gA1 = A + (row0 + ar1) * 512 + ac1;
    const u16* gB0 = Bw + (size_t)(col0 + ar0) * 512 + ac0;
    const u16* gB1 = Bw + (size_t)(col0 + ar1) * 512 + ac1;

#define QKV_STAGE(buf, k0) do {                                   \
        u16* As_ = SMF + (buf) * 16384;                           \
        u16* Bs_ = As_ + 8192;                                    \
        gld16(gA0 + (k0), As_ + wave * 512);                      \
        gld16(gA1 + (k0), As_ + 4096 + wave * 512);               \
        gld16(gB0 + (k0), Bs_ + wave * 512);                      \
        gld16(gB1 + (k0), Bs_ + 4096 + wave * 512);               \
    } while (0)

    QKV_STAGE(0, 0);
    __syncthreads();               // implicit vmcnt(0): buf0 ready
#pragma unroll
    for (int t = 0; t < 8; ++t) {
        const int cur = t & 1;     // STATIC buffer index (unrolled)
        if (t < 7) QKV_STAGE(cur ^ 1, (t + 1) * 64);    // prefetch next tile
        const u16* As_ = SMF + cur * 16384;
        const u16* Bs_ = As_ + 8192;
#pragma unroll
        for (int kk = 0; kk < 2; ++kk) {
            const int cbase = kk * 32 + quad * 8;
            bf16x8 af[2], bfr[4];
#pragma unroll
            for (int mi = 0; mi < 2; ++mi) {
                const int r = wr + mi * 16 + frow;
                af[mi] = *(const bf16x8*)&As_[r * 64 + (cbase ^ ((r & 7) * 8))];
            }
#pragma unroll
            for (int ni = 0; ni < 4; ++ni) {
                const int r = wc + ni * 16 + frow;
                bfr[ni] = *(const bf16x8*)&Bs_[r * 64 + (cbase ^ ((r & 7) * 8))];
            }
#pragma unroll
            for (int mi = 0; mi < 2; ++mi)
#pragma unroll
                for (int ni = 0; ni < 4; ++ni)
                    acc[mi][ni] = __builtin_amdgcn_mfma_f32_16x16x32_bf16(af[mi], bfr[ni], acc[mi][ni], 0, 0, 0);
        }
        __syncthreads();           // drains vmcnt(0): prefetched buf ready
    }
#undef QKV_STAGE

    if (col0 < 512) {
        // q epilogue: C/D layout col = lane&15, row = quad*4 + reg [m89/m91]
#pragma unroll
        for (int mi = 0; mi < 2; ++mi) {
#pragma unroll
            for (int ni = 0; ni < 4; ++ni) {
                const int c = col0 + wc + ni * 16 + frow;
                const size_t rbase = row0 + wr + mi * 16 + quad * 4;
#pragma unroll
                for (int reg = 0; reg < 4; ++reg)
                    Cq[(rbase + reg) * 512 + c] = f2bf(act_fn(acc[mi][ni][reg]));
            }
        }
        return;
    }

    // ---- kv epilogue (head h = nt-4). KT/VT overlay buf0 (u16 0..10367);
    // the final loop iteration (t=7) computed buf1 (u16 16384..32767) and
    // ended with __syncthreads -> disjoint & ordered.
    u16* KT = SMF;                 // [64][72] k^T
    u16* VT = SMF + 4608;          // [80][72] v^T; row 64 = ones
    for (int i = tid; i < 16 * 72; i += 512)
        VT[64 * 72 + i] = (i < 64) ? (u16)0x3F80 : (u16)0;

    const bool is_k = (wc == 0);   // even waves hold k cols, odd hold v cols
    f32x4 kvacc[5] = {};           // e-tiles; meaningful on waves 0..3

#pragma unroll
    for (int half = 0; half < 2; ++half) {
        __syncthreads();           // prior KT/VT readers (and ones writes) done
        if ((wave >> 2) == half) { // waves 0-3: token rows 0..63; 4-7: 64..127
#pragma unroll
            for (int mi = 0; mi < 2; ++mi) {
                const int n0 = wr + mi * 16 + quad * 4 - half * 64;   // 0..60
#pragma unroll
                for (int ni = 0; ni < 4; ++ni) {
                    const int cl = wc + ni * 16 + frow;               // 0..127
                    u16x4 o2;
#pragma unroll
                    for (int reg = 0; reg < 4; ++reg) {
                        float v = acc[mi][ni][reg];
                        if (is_k) v = act_fn(v);
                        o2[reg] = f2bf(v);
                    }
                    if (is_k) *(u16x4*)&KT[cl * 72 + n0] = o2;
                    else      *(u16x4*)&VT[(cl - 64) * 72 + n0] = o2;
                }
            }
        }
        __syncthreads();
        // kv[d][e] += KT@VT^T over this half's 64 tokens (waves 0-3 only)
        if (wave < 4) {
#pragma unroll
            for (int c = 0; c < 2; ++c) {
                bf16x8 af2 = *(const bf16x8*)&KT[(wave * 16 + frow) * 72 + c * 32 + quad * 8];
#pragma unroll
                for (int et = 0; et < 5; ++et) {
                    bf16x8 bf2 = *(const bf16x8*)&VT[(et * 16 + frow) * 72 + c * 32 + quad * 8];
                    kvacc[et] = __builtin_amdgcn_mfma_f32_16x16x32_bf16(af2, bf2, kvacc[et], 0, 0, 0);
                }
            }
        }
    }

    if (wave < 4) {
        const int b = mt >> 5, h = nt - 4;
        float* dst = kvglob + (size_t)(b * 8 + h) * 5120;
#pragma unroll
        for (int et = 0; et < 5; ++et) {
            const int e = et * 16 + frow;
            if (e <= 64) {
#pragma unroll
                for (int reg = 0; reg < 4; ++reg) {
                    const int d = wave * 16 + quad * 4 + reg;
                    atomicAdd(&dst[d * 80 + e], kvacc[et][reg]);
                }
            }
        }
    }
}

// ---------------------------------------------------------------------------
// make_P: one block per (b,h). P_b[c][h*64+d] = sum_e Wout[c][h*64+e]*kv[d][e]
// via MFMA (A = Wout rows from global, L2-resident; B = kv rows from LDS).
// Also extracts ksum_cat[b][h*64+d] = kvglob col e=64. 512x64x64 GEMM/block.
// ---------------------------------------------------------------------------
__global__ __launch_bounds__(256) void make_P(const float* __restrict__ kvglob,
                                              const u16* __restrict__ wo,
                                              u16* __restrict__ P,
                                              u16* __restrict__ ksum)
{
    __shared__ u16 kvb[64 * 72];   // kv[d][e] bf16, pad 72
    const int bh = blockIdx.x, b = bh >> 3, h = bh & 7;
    const int tid = threadIdx.x, wave = tid >> 6, lane = tid & 63;
    const int frow = lane & 15, quad = lane >> 4;
    const float* src = kvglob + (size_t)bh * 5120;

    for (int i = tid; i < 4096; i += 256)
        kvb[(i >> 6) * 72 + (i & 63)] = f2bf(src[(i >> 6) * 80 + (i & 63)]);
    if (tid < 64) ksum[bh * 64 + tid] = f2bf(src[tid * 80 + 64]);
    __syncthreads();

    f32x4 acc[8][4] = {};          // m = Wout-row tile (wave*128..+128), n = d
    const int m0 = wave * 128;
#pragma unroll
    for (int k2 = 0; k2 < 2; ++k2) {           // e-chunk of 32
        bf16x8 bfr[4];
#pragma unroll
        for (int ni = 0; ni < 4; ++ni)
            bfr[ni] = *(const bf16x8*)&kvb[(ni * 16 + frow) * 72 + k2 * 32 + quad * 8];
#pragma unroll
        for (int mi = 0; mi < 8; ++mi) {
            bf16x8 af = *(const bf16x8*)&wo[(size_t)(m0 + mi * 16 + frow) * 512 + h * 64 + k2 * 32 + quad * 8];
#pragma unroll
            for (int ni = 0; ni < 4; ++ni)
                acc[mi][ni] = __builtin_amdgcn_mfma_f32_16x16x32_bf16(af, bfr[ni], acc[mi][ni], 0, 0, 0);
        }
    }

    u16* Pb = P + (size_t)b * 262144;
#pragma unroll
    for (int mi = 0; mi < 8; ++mi) {
#pragma unroll
        for (int ni = 0; ni < 4; ++ni) {
            const int d = ni * 16 + frow;      // C/D: col = lane&15
#pragma unroll
            for (int reg = 0; reg < 4; ++reg) {
                const int c = m0 + mi * 16 + quad * 4 + reg;
                Pb[(size_t)c * 512 + h * 64 + d] = f2bf(acc[mi][ni][reg]);
            }
        }
    }
}

// ---------------------------------------------------------------------------
// gemm_final: out[t][c] (fp32): per K-step t (= head h = t), compute the
// step's unscaled partial sacc and den dacc (broadcast-B MFMA vs ksum chunk:
// every acc column = den(row)), then fold oacc += sacc * 1/max(den,eps).
// B matrix is per-batch P (L2-resident). BK=64 + T2 swizzle as gemm_qkv.
// T1 XCD swizzle (cpx=256). K-loop FULLY UNROLLED, cur = t&1 static.
// ---------------------------------------------------------------------------
__global__ __launch_bounds__(512, 4) void gemm_final(const u16* __restrict__ A,
                                                     const u16* __restrict__ P,
                                                     float* __restrict__ C,
                                                     const float* __restrict__ bias,
                                                     const u16* __restrict__ ksum)
{
    __shared__ u16 SMF[32768];
    __shared__ u16 ksumL[512];
    const int id = blockIdx.y * 4 + blockIdx.x;         // linear dispatch id
    const int o  = (id & 7) * 256 + (id >> 3);          // T1 bijective remap
    const int nt = o & 3;          // col-tile (fastest within XCD chunk)
    const int mt = o >> 2;         // M-tile
    const size_t row0 = (size_t)mt * 128;
    const int col0 = nt * 128;
    const int bb = mt >> 5;
    const u16* Bw = P + (size_t)bb * 262144;
    const int tid  = threadIdx.x;
    const int wave = tid >> 6, lane = tid & 63;
    const int wr = (wave >> 1) * 32, wc = (wave & 1) * 64;
    const int frow = lane & 15, quad = lane >> 4;

    f32x4 oacc[2][4] = {};         // z-scaled running output

    const int ch0 = wave * 64 + lane, ch1 = 512 + ch0;
    const int ar0 = ch0 >> 3, ac0 = ((ch0 & 7) ^ (ar0 & 7)) * 8;
    const int ar1 = ch1 >> 3, ac1 = ((ch1 & 7) ^ (ar1 & 7)) * 8;
    const u16* gA0 = A + (row0 + ar0) * 512 + ac0;
    const u16* gA1 = A + (row0 + ar1) * 512 + ac1;
    const u16* gB0 = Bw + (size_t)(col0 + ar0) * 512 + ac0;
    const u16* gB1 = Bw + (size_t)(col0 + ar1) * 512 + ac1;

#define OUT_STAGE(buf, k0) do {                                   \
        u16* As_ = SMF + (buf) * 16384;                           \
        u16* Bs_ = As_ + 8192;                                    \
        gld16(gA0 + (k0), As_ + wave * 512);                      \
        gld16(gA1 + (k0), As_ + 4096 + wave * 512);               \
        gld16(gB0 + (k0), Bs_ + wave * 512);                      \
        gld16(gB1 + (k0), Bs_ + 4096 + wave * 512);               \
    } while (0)

    OUT_STAGE(0, 0);
    if (tid < 64) *(u16x8*)&ksumL[tid * 8] = *(const u16x8*)&ksum[bb * 512 + tid * 8];
    __syncthreads();
#pragma unroll
    for (int t = 0; t < 8; ++t) {  // one K-step = one head h = t
        const int cur = t & 1;     // STATIC buffer index (unrolled)
        if (t < 7) OUT_STAGE(cur ^ 1, (t + 1) * 64);
        const u16* As_ = SMF + cur * 16384;
        const u16* Bs_ = As_ + 8192;
        f32x4 sacc[2][4] = {};     // this head's unscaled partial
        f32x4 dacc[2] = {};        // den: broadcast-B -> all cols = den(row)
#pragma unroll
        for (int kk = 0; kk < 2; ++kk) {
            const int cbase = kk * 32 + quad * 8;
            bf16x8 af[2], bfr[4];
#pragma unroll
            for (int mi = 0; mi < 2; ++mi) {
                const int r = wr + mi * 16 + frow;
                af[mi] = *(const bf16x8*)&As_[r * 64 + (cbase ^ ((r & 7) * 8))];
            }
#pragma unroll
            for (int ni = 0; ni < 4; ++ni) {
                const int r = wc + ni * 16 + frow;
                bfr[ni] = *(const bf16x8*)&Bs_[r * 64 + (cbase ^ ((r & 7) * 8))];
            }
            bf16x8 kf = *(const bf16x8*)&ksumL[t * 64 + kk * 32 + quad * 8];
#pragma unroll
            for (int mi = 0; mi < 2; ++mi) {
                dacc[mi] = __builtin_amdgcn_mfma_f32_16x16x32_bf16(af[mi], kf, dacc[mi], 0, 0, 0);
#pragma unroll
                for (int ni = 0; ni < 4; ++ni)
                    sacc[mi][ni] = __builtin_amdgcn_mfma_f32_16x16x32_bf16(af[mi], bfr[ni], sacc[mi][ni], 0, 0, 0);
            }
        }
        // fold: oacc += sacc * z_h ; den(row=quad*4+reg) = dacc[mi][reg]
#pragma unroll
        for (int mi = 0; mi < 2; ++mi)
#pragma unroll
            for (int reg = 0; reg < 4; ++reg) {
                const float z = 1.0f / fmaxf(dacc[mi][reg], 1e-4f);
#pragma unroll
                for (int ni = 0; ni < 4; ++ni)
                    oacc[mi][ni][reg] += sacc[mi][ni][reg] * z;
            }
        __syncthreads();
    }
#undef OUT_STAGE

#pragma unroll
    for (int mi = 0; mi < 2; ++mi) {
#pragma unroll
        for (int ni = 0; ni < 4; ++ni) {
            const int c = col0 + wc + ni * 16 + frow;
            const float bv = bias[c];
            const size_t rbase = row0 + wr + mi * 16 + quad * 4;
#pragma unroll
            for (int reg = 0; reg < 4; ++reg)
                C[(rbase + reg) * 512 + c] = oacc[mi][ni][reg] + bv;
        }
    }
}

extern "C" void kernel_launch(void* const* d_in, const int* in_sizes, int n_in,
                              void* d_out, int out_size, void* d_ws, size_t ws_size,
                              hipStream_t stream)
{
    const float* x    = (const float*)d_in[0];   // [65536, 512] fp32
    const float* Wqkv = (const float*)d_in[1];   // [1536, 512]  fp32
    const float* Wout = (const float*)d_in[2];   // [512, 512]   fp32
    const float* bout = (const float*)d_in[3];   // [512]        fp32
    float* out = (float*)d_out;                  // [65536, 512] fp32
    char* ws = (char*)d_ws;

    u16*   wq_bf  = (u16*)ws;                      //   1,572,864 B
    u16*   wo_bf  = (u16*)(ws + 1572864ull);       //     524,288 B
    u16*   wsq    = (u16*)(ws + 2097152ull);       //  67,108,864 B
    u16*   xb     = (u16*)(ws + 69206016ull);      //  67,108,864 B (P reuses this)
    u16*   P      = xb;                            //   8,388,608 B (after gemm_qkv)
    float* kvglob = (float*)(ws + 136314880ull);   //   2,621,440 B
    u16*   ksum   = (u16*)(ws + 138936320ull);     //      65,536 B -> 139,001,856

    // 0) x -> bf16, weights -> bf16 (W_qkv row-permuted), zero kv accumulator
    convert_all<<<17216, 256, 0, stream>>>(x, Wqkv, Wout, xb, wq_bf, wo_bf, kvglob);
    // 1) fused qkv GEMM: q' -> wsq ; per-head kv outer-product -> kvglob
    gemm_qkv<<<dim3(12, 512), 512, 0, stream>>>(xb, wq_bf, wsq, kvglob);
    // 2) P_b = kv_h @ Wout_h (per bh) ; extract ksum  (xb dead -> P reuses it)
    make_P<<<128, 256, 0, stream>>>(kvglob, wo_bf, P, ksum);
    // 3) out = sum_h z_h .* (q' @ P_b^T)_h + b_out  (z fused in-GEMM, fp32)
    gemm_final<<<dim3(4, 512), 512, 0, stream>>>(wsq, P, out, bout, ksum);
}

// Round 14
// 439.882 us; speedup vs baseline: 1.7838x; 1.7838x over previous
//
#include <hip/hip_runtime.h>

// LinearAttention: b=16, n=4096, dim=512, H=8, D=64, inner=512. T=65536 tokens.
// I/O dtype: fp32 (per reference). Compute: bf16 MFMA, fp32 accumulate.
//
// Algebraic form: out[t] = sum_h z_h(t) * (q'_h[t] @ kv_h) @ Wout_h
//                        = (z .* q') @ Pcat,  Pcat_b[c][h*64+d] = sum_e kv_h[d][e] Wout[c][h*64+e]
// z applied to the fp32 accumulator of gemm_final (den via broadcast-B MFMA).
// R12 A/B proved the den fusion is net-positive vs a standalone apply_z pass.
//
// ws layout (~139 MiB):
//   wq_bf  [1536x512 bf16]  W_qkv converted + ROW-PERMUTED (q | per-head k|v)
//   wo_bf  [ 512x512 bf16]  converted W_out
//   wsq    [65536x512 bf16] q' = act(x@Wq^T)  (UNscaled; z applied in gemm_final)
//   xb     [65536x512 bf16] x converted once; REUSED as P after gemm_qkv
//   kvglob [128 x 64x80 f32] kv accumulator (atomicAdd), col e=64 = ksum
//   ksum_bf[16 x 512 bf16]  per-batch concatenated k-sum (h*64+d)
//
// THIS IS THE R11 KERNEL (419.6 us, best verified), restored after two failed
// experiments:
//  - R12: replacing den-fusion with standalone apply_z REGRESSED +13 us.
//  - R13: full K-loop unroll (static cur) REGRESSED +365 us — 8 live copies
//    of per-step sacc/dacc spilled to scratch (WRITE_SIZE 962 MB, MfmaUtil
//    4%). Rolled loops with dynamic cur are the correct codegen here.
// History: 617 baseline -> 478 (2-phase gld_lds GEMMs, P-refactor) -> 448.7
// (BK=64 + T2 both-sides swizzle) -> 419.6 (T1 bijective XCD remap: qkv
// FETCH 266->39 MB).

typedef unsigned short u16;
typedef u16 u16x4 __attribute__((ext_vector_type(4)));
typedef u16 u16x8 __attribute__((ext_vector_type(8)));
typedef __bf16 bf16x8 __attribute__((ext_vector_type(8)));
typedef float f32x4 __attribute__((ext_vector_type(4)));

__device__ __forceinline__ float bf2f(u16 x) {
    union { unsigned u; float f; } t; t.u = ((unsigned)x) << 16; return t.f;
}
__device__ __forceinline__ u16 f2bf(float f) {
    union { float f; unsigned u; } t; t.f = f;
    unsigned r = t.u + 0x7fffu + ((t.u >> 16) & 1u);   // RNE
    return (u16)(r >> 16);
}
__device__ __forceinline__ float act_fn(float v) {     // 1 + elu
    return v > 0.0f ? v + 1.0f : __expf(v);
}
__device__ __forceinline__ void cvt8(const float* __restrict__ s, u16* __restrict__ d) {
    f32x4 lo = *(const f32x4*)s;
    f32x4 hi = *(const f32x4*)(s + 4);
    u16x8 o = { f2bf(lo[0]), f2bf(lo[1]), f2bf(lo[2]), f2bf(lo[3]),
                f2bf(hi[0]), f2bf(hi[1]), f2bf(hi[2]), f2bf(hi[3]) };
    *(u16x8*)d = o;
}
// async global->LDS, 16B per lane. LDS dest = wave-uniform base + lane*16.
__device__ __forceinline__ void gld16(const u16* g, u16* l) {
    __builtin_amdgcn_global_load_lds(
        (__attribute__((address_space(1))) const void*)g,
        (__attribute__((address_space(3))) void*)l, 16, 0, 0);
}

// ---------------------------------------------------------------------------
// convert_all: x (4,194,304 x8 units) -> xb ; W_qkv (98,304 units) -> wq_bf
// with the head-interleaved row permutation ; W_out (32,768) -> wo_bf ;
// zero kvglob (81,920 f32 = 10,240 x8 units). 17,216 x 256 exact.
// ---------------------------------------------------------------------------
__global__ __launch_bounds__(256) void convert_all(const float* __restrict__ x,
                                                   const float* __restrict__ Wqkv,
                                                   const float* __restrict__ Wout,
                                                   u16* __restrict__ xb,
                                                   u16* __restrict__ wq,
                                                   u16* __restrict__ wo,
                                                   float* __restrict__ kvg)
{
    size_t u = (size_t)blockIdx.x * 256 + threadIdx.x;
    if (u < 4194304ull) {
        cvt8(x + u * 8, xb + u * 8);
    } else if (u < 4292608ull) {
        u -= 4194304ull;                       // dest unit within wq_bf
        const int drow = (int)(u >> 6);
        int srow;
        if (drow < 512) srow = drow;
        else {
            const int t = drow - 512, h = t >> 7, j = t & 127;
            srow = (j < 64) ? (512 + h * 64 + j) : (1024 + h * 64 + (j - 64));
        }
        cvt8(Wqkv + (size_t)srow * 512 + (u & 63) * 8, wq + u * 8);
    } else if (u < 4325376ull) {
        u -= 4292608ull; cvt8(Wout + u * 8, wo + u * 8);
    } else {
        u -= 4325376ull;
        f32x4 z = { 0.f, 0.f, 0.f, 0.f };
        *(f32x4*)&kvg[u * 8] = z;
        *(f32x4*)&kvg[u * 8 + 4] = z;
    }
}

// ---------------------------------------------------------------------------
// gemm_qkv: C128x128 tile of x @ Wqkv_perm^T, K=512, 8 K-steps of BK=64.
// 2-phase __syncthreads double-buffer (proven), 512 thr / 8 waves; wave owns
// 32x64 (acc 2x4). T2 swizzle both-sides (global source pre-swizzled, LDS
// linear, ds_read swizzled). T1 XCD swizzle: o = (id%8)*768 + id/8, nt=o%12,
// mt=o/12 — bijective (6144 = 8*768).
// Col-tiles 0..3 -> q: act + store to wsq.  Col-tiles 4..11 -> head h=nt-4:
// kv epilogue (KT/VT overlay buf0; last compute reads buf1 -> disjoint).
// Measured R11: 146 us, FETCH 39 MB, MfmaUtil 32.5%, conflicts 2.6M.
// ---------------------------------------------------------------------------
__global__ __launch_bounds__(512, 4) void gemm_qkv(const u16* __restrict__ A,
                                                   const u16* __restrict__ Bw,
                                                   u16* __restrict__ Cq,
                                                   float* __restrict__ kvglob)
{
    __shared__ u16 SMF[32768];     // 64 KB: buf b at b*16384 (As 8192 | Bs 8192)
    const int id = blockIdx.y * 12 + blockIdx.x;        // linear dispatch id
    const int o  = (id & 7) * 768 + (id >> 3);          // T1 bijective remap
    const int nt = o % 12;         // col-tile (fastest within XCD chunk)
    const int mt = o / 12;         // M-tile
    const size_t row0 = (size_t)mt * 128;
    const int col0 = nt * 128;
    const int tid = threadIdx.x, wave = tid >> 6, lane = tid & 63;
    const int frow = lane & 15, quad = lane >> 4;
    const int wr = (wave >> 1) * 32, wc = (wave & 1) * 64;

    f32x4 acc[2][4] = {};

    // staging chunks (16B each): ch in [0,1024) covers 128x64; row = ch>>3;
    // LDS linear at u16 ch*8; SOURCE col16 = (ch&7)^(row&7)  [T2 involution]
    const int ch0 = wave * 64 + lane, ch1 = 512 + ch0;
    const int ar0 = ch0 >> 3, ac0 = ((ch0 & 7) ^ (ar0 & 7)) * 8;
    const int ar1 = ch1 >> 3, ac1 = ((ch1 & 7) ^ (ar1 & 7)) * 8;
    const u16* gA0 = A + (row0 + ar0) * 512 + ac0;
    const u16* gA1 = A + (row0 + ar1) * 512 + ac1;
    const u16* gB0 = Bw + (size_t)(col0 + ar0) * 512 + ac0;
    const u16* gB1 = Bw + (size_t)(col0 + ar1) * 512 + ac1;

#define QKV_STAGE(buf, k0) do {                                   \
        u16* As_ = SMF + (buf) * 16384;                           \
        u16* Bs_ = As_ + 8192;                                    \
        gld16(gA0 + (k0), As_ + wave * 512);                      \
        gld16(gA1 + (k0), As_ + 4096 + wave * 512);               \
        gld16(gB0 + (k0), Bs_ + wave * 512);                      \
        gld16(gB1 + (k0), Bs_ + 4096 + wave * 512);               \
    } while (0)

    QKV_STAGE(0, 0);
    __syncthreads();               // implicit vmcnt(0): buf0 ready
    int cur = 0;
    for (int t = 0; t < 8; ++t) {
        if (t < 7) QKV_STAGE(cur ^ 1, (t + 1) * 64);    // prefetch next tile
        const u16* As_ = SMF + cur * 16384;
        const u16* Bs_ = As_ + 8192;
#pragma unroll
        for (int kk = 0; kk < 2; ++kk) {
            const int cbase = kk * 32 + quad * 8;
            bf16x8 af[2], bfr[4];
#pragma unroll
            for (int mi = 0; mi < 2; ++mi) {
                const int r = wr + mi * 16 + frow;
                af[mi] = *(const bf16x8*)&As_[r * 64 + (cbase ^ ((r & 7) * 8))];
            }
#pragma unroll
            for (int ni = 0; ni < 4; ++ni) {
                const int r = wc + ni * 16 + frow;
                bfr[ni] = *(const bf16x8*)&Bs_[r * 64 + (cbase ^ ((r & 7) * 8))];
            }
#pragma unroll
            for (int mi = 0; mi < 2; ++mi)
#pragma unroll
                for (int ni = 0; ni < 4; ++ni)
                    acc[mi][ni] = __builtin_amdgcn_mfma_f32_16x16x32_bf16(af[mi], bfr[ni], acc[mi][ni], 0, 0, 0);
        }
        __syncthreads();           // drains vmcnt(0): prefetched buf ready
        cur ^= 1;
    }
#undef QKV_STAGE

    if (col0 < 512) {
        // q epilogue: C/D layout col = lane&15, row = quad*4 + reg [m89/m91]
#pragma unroll
        for (int mi = 0; mi < 2; ++mi) {
#pragma unroll
            for (int ni = 0; ni < 4; ++ni) {
                const int c = col0 + wc + ni * 16 + frow;
                const size_t rbase = row0 + wr + mi * 16 + quad * 4;
#pragma unroll
                for (int reg = 0; reg < 4; ++reg)
                    Cq[(rbase + reg) * 512 + c] = f2bf(act_fn(acc[mi][ni][reg]));
            }
        }
        return;
    }

    // ---- kv epilogue (head h = nt-4). KT/VT overlay buf0 (u16 0..10367);
    // the final loop iteration (t=7) computed buf1 (u16 16384..32767) and
    // ended with __syncthreads -> disjoint & ordered.
    u16* KT = SMF;                 // [64][72] k^T
    u16* VT = SMF + 4608;          // [80][72] v^T; row 64 = ones
    for (int i = tid; i < 16 * 72; i += 512)
        VT[64 * 72 + i] = (i < 64) ? (u16)0x3F80 : (u16)0;

    const bool is_k = (wc == 0);   // even waves hold k cols, odd hold v cols
    f32x4 kvacc[5] = {};           // e-tiles; meaningful on waves 0..3

#pragma unroll
    for (int half = 0; half < 2; ++half) {
        __syncthreads();           // prior KT/VT readers (and ones writes) done
        if ((wave >> 2) == half) { // waves 0-3: token rows 0..63; 4-7: 64..127
#pragma unroll
            for (int mi = 0; mi < 2; ++mi) {
                const int n0 = wr + mi * 16 + quad * 4 - half * 64;   // 0..60
#pragma unroll
                for (int ni = 0; ni < 4; ++ni) {
                    const int cl = wc + ni * 16 + frow;               // 0..127
                    u16x4 o2;
#pragma unroll
                    for (int reg = 0; reg < 4; ++reg) {
                        float v = acc[mi][ni][reg];
                        if (is_k) v = act_fn(v);
                        o2[reg] = f2bf(v);
                    }
                    if (is_k) *(u16x4*)&KT[cl * 72 + n0] = o2;
                    else      *(u16x4*)&VT[(cl - 64) * 72 + n0] = o2;
                }
            }
        }
        __syncthreads();
        // kv[d][e] += KT@VT^T over this half's 64 tokens (waves 0-3 only)
        if (wave < 4) {
#pragma unroll
            for (int c = 0; c < 2; ++c) {
                bf16x8 af2 = *(const bf16x8*)&KT[(wave * 16 + frow) * 72 + c * 32 + quad * 8];
#pragma unroll
                for (int et = 0; et < 5; ++et) {
                    bf16x8 bf2 = *(const bf16x8*)&VT[(et * 16 + frow) * 72 + c * 32 + quad * 8];
                    kvacc[et] = __builtin_amdgcn_mfma_f32_16x16x32_bf16(af2, bf2, kvacc[et], 0, 0, 0);
                }
            }
        }
    }

    if (wave < 4) {
        const int b = mt >> 5, h = nt - 4;
        float* dst = kvglob + (size_t)(b * 8 + h) * 5120;
#pragma unroll
        for (int et = 0; et < 5; ++et) {
            const int e = et * 16 + frow;
            if (e <= 64) {
#pragma unroll
                for (int reg = 0; reg < 4; ++reg) {
                    const int d = wave * 16 + quad * 4 + reg;
                    atomicAdd(&dst[d * 80 + e], kvacc[et][reg]);
                }
            }
        }
    }
}

// ---------------------------------------------------------------------------
// make_P: one block per (b,h). P_b[c][h*64+d] = sum_e Wout[c][h*64+e]*kv[d][e]
// via MFMA (A = Wout rows from global, L2-resident; B = kv rows from LDS).
// Also extracts ksum_cat[b][h*64+d] = kvglob col e=64. 512x64x64 GEMM/block.
// ---------------------------------------------------------------------------
__global__ __launch_bounds__(256) void make_P(const float* __restrict__ kvglob,
                                              const u16* __restrict__ wo,
                                              u16* __restrict__ P,
                                              u16* __restrict__ ksum)
{
    __shared__ u16 kvb[64 * 72];   // kv[d][e] bf16, pad 72
    const int bh = blockIdx.x, b = bh >> 3, h = bh & 7;
    const int tid = threadIdx.x, wave = tid >> 6, lane = tid & 63;
    const int frow = lane & 15, quad = lane >> 4;
    const float* src = kvglob + (size_t)bh * 5120;

    for (int i = tid; i < 4096; i += 256)
        kvb[(i >> 6) * 72 + (i & 63)] = f2bf(src[(i >> 6) * 80 + (i & 63)]);
    if (tid < 64) ksum[bh * 64 + tid] = f2bf(src[tid * 80 + 64]);
    __syncthreads();

    f32x4 acc[8][4] = {};          // m = Wout-row tile (wave*128..+128), n = d
    const int m0 = wave * 128;
#pragma unroll
    for (int k2 = 0; k2 < 2; ++k2) {           // e-chunk of 32
        bf16x8 bfr[4];
#pragma unroll
        for (int ni = 0; ni < 4; ++ni)
            bfr[ni] = *(const bf16x8*)&kvb[(ni * 16 + frow) * 72 + k2 * 32 + quad * 8];
#pragma unroll
        for (int mi = 0; mi < 8; ++mi) {
            bf16x8 af = *(const bf16x8*)&wo[(size_t)(m0 + mi * 16 + frow) * 512 + h * 64 + k2 * 32 + quad * 8];
#pragma unroll
            for (int ni = 0; ni < 4; ++ni)
                acc[mi][ni] = __builtin_amdgcn_mfma_f32_16x16x32_bf16(af, bfr[ni], acc[mi][ni], 0, 0, 0);
        }
    }

    u16* Pb = P + (size_t)b * 262144;
#pragma unroll
    for (int mi = 0; mi < 8; ++mi) {
#pragma unroll
        for (int ni = 0; ni < 4; ++ni) {
            const int d = ni * 16 + frow;      // C/D: col = lane&15
#pragma unroll
            for (int reg = 0; reg < 4; ++reg) {
                const int c = m0 + mi * 16 + quad * 4 + reg;
                Pb[(size_t)c * 512 + h * 64 + d] = f2bf(acc[mi][ni][reg]);
            }
        }
    }
}

// ---------------------------------------------------------------------------
// gemm_final: out[t][c] (fp32): per K-step t (= head h = t), compute the
// step's unscaled partial sacc and den dacc (broadcast-B MFMA vs ksum chunk:
// every acc column = den(row)), then fold oacc += sacc * 1/max(den,eps).
// B matrix is per-batch P (L2-resident). BK=64 + T2 swizzle as gemm_qkv.
// T1 XCD swizzle: o = (id%8)*256 + id/8, nt=o&3, mt=o>>2 (2048 = 8*256).
// ROLLED loop with dynamic cur — R13 proved full unroll spills to scratch.
// ---------------------------------------------------------------------------
__global__ __launch_bounds__(512, 4) void gemm_final(const u16* __restrict__ A,
                                                     const u16* __restrict__ P,
                                                     float* __restrict__ C,
                                                     const float* __restrict__ bias,
                                                     const u16* __restrict__ ksum)
{
    __shared__ u16 SMF[32768];
    __shared__ u16 ksumL[512];
    const int id = blockIdx.y * 4 + blockIdx.x;         // linear dispatch id
    const int o  = (id & 7) * 256 + (id >> 3);          // T1 bijective remap
    const int nt = o & 3;          // col-tile (fastest within XCD chunk)
    const int mt = o >> 2;         // M-tile
    const size_t row0 = (size_t)mt * 128;
    const int col0 = nt * 128;
    const int bb = mt >> 5;
    const u16* Bw = P + (size_t)bb * 262144;
    const int tid  = threadIdx.x;
    const int wave = tid >> 6, lane = tid & 63;
    const int wr = (wave >> 1) * 32, wc = (wave & 1) * 64;
    const int frow = lane & 15, quad = lane >> 4;

    f32x4 oacc[2][4] = {};         // z-scaled running output

    const int ch0 = wave * 64 + lane, ch1 = 512 + ch0;
    const int ar0 = ch0 >> 3, ac0 = ((ch0 & 7) ^ (ar0 & 7)) * 8;
    const int ar1 = ch1 >> 3, ac1 = ((ch1 & 7) ^ (ar1 & 7)) * 8;
    const u16* gA0 = A + (row0 + ar0) * 512 + ac0;
    const u16* gA1 = A + (row0 + ar1) * 512 + ac1;
    const u16* gB0 = Bw + (size_t)(col0 + ar0) * 512 + ac0;
    const u16* gB1 = Bw + (size_t)(col0 + ar1) * 512 + ac1;

#define OUT_STAGE(buf, k0) do {                                   \
        u16* As_ = SMF + (buf) * 16384;                           \
        u16* Bs_ = As_ + 8192;                                    \
        gld16(gA0 + (k0), As_ + wave * 512);                      \
        gld16(gA1 + (k0), As_ + 4096 + wave * 512);               \
        gld16(gB0 + (k0), Bs_ + wave * 512);                      \
        gld16(gB1 + (k0), Bs_ + 4096 + wave * 512);               \
    } while (0)

    OUT_STAGE(0, 0);
    if (tid < 64) *(u16x8*)&ksumL[tid * 8] = *(const u16x8*)&ksum[bb * 512 + tid * 8];
    __syncthreads();
    int cur = 0;
    for (int t = 0; t < 8; ++t) {  // one K-step = one head h = t
        if (t < 7) OUT_STAGE(cur ^ 1, (t + 1) * 64);
        const u16* As_ = SMF + cur * 16384;
        const u16* Bs_ = As_ + 8192;
        f32x4 sacc[2][4] = {};     // this head's unscaled partial
        f32x4 dacc[2] = {};        // den: broadcast-B -> all cols = den(row)
#pragma unroll
        for (int kk = 0; kk < 2; ++kk) {
            const int cbase = kk * 32 + quad * 8;
            bf16x8 af[2], bfr[4];
#pragma unroll
            for (int mi = 0; mi < 2; ++mi) {
                const int r = wr + mi * 16 + frow;
                af[mi] = *(const bf16x8*)&As_[r * 64 + (cbase ^ ((r & 7) * 8))];
            }
#pragma unroll
            for (int ni = 0; ni < 4; ++ni) {
                const int r = wc + ni * 16 + frow;
                bfr[ni] = *(const bf16x8*)&Bs_[r * 64 + (cbase ^ ((r & 7) * 8))];
            }
            bf16x8 kf = *(const bf16x8*)&ksumL[t * 64 + kk * 32 + quad * 8];
#pragma unroll
            for (int mi = 0; mi < 2; ++mi) {
                dacc[mi] = __builtin_amdgcn_mfma_f32_16x16x32_bf16(af[mi], kf, dacc[mi], 0, 0, 0);
#pragma unroll
                for (int ni = 0; ni < 4; ++ni)
                    sacc[mi][ni] = __builtin_amdgcn_mfma_f32_16x16x32_bf16(af[mi], bfr[ni], sacc[mi][ni], 0, 0, 0);
            }
        }
        // fold: oacc += sacc * z_h ; den(row=quad*4+reg) = dacc[mi][reg]
#pragma unroll
        for (int mi = 0; mi < 2; ++mi)
#pragma unroll
            for (int reg = 0; reg < 4; ++reg) {
                const float z = 1.0f / fmaxf(dacc[mi][reg], 1e-4f);
#pragma unroll
                for (int ni = 0; ni < 4; ++ni)
                    oacc[mi][ni][reg] += sacc[mi][ni][reg] * z;
            }
        __syncthreads();
        cur ^= 1;
    }
#undef OUT_STAGE

#pragma unroll
    for (int mi = 0; mi < 2; ++mi) {
#pragma unroll
        for (int ni = 0; ni < 4; ++ni) {
            const int c = col0 + wc + ni * 16 + frow;
            const float bv = bias[c];
            const size_t rbase = row0 + wr + mi * 16 + quad * 4;
#pragma unroll
            for (int reg = 0; reg < 4; ++reg)
                C[(rbase + reg) * 512 + c] = oacc[mi][ni][reg] + bv;
        }
    }
}

extern "C" void kernel_launch(void* const* d_in, const int* in_sizes, int n_in,
                              void* d_out, int out_size, void* d_ws, size_t ws_size,
                              hipStream_t stream)
{
    const float* x    = (const float*)d_in[0];   // [65536, 512] fp32
    const float* Wqkv = (const float*)d_in[1];   // [1536, 512]  fp32
    const float* Wout = (const float*)d_in[2];   // [512, 512]   fp32
    const float* bout = (const float*)d_in[3];   // [512]        fp32
    float* out = (float*)d_out;                  // [65536, 512] fp32
    char* ws = (char*)d_ws;

    u16*   wq_bf  = (u16*)ws;                      //   1,572,864 B
    u16*   wo_bf  = (u16*)(ws + 1572864ull);       //     524,288 B
    u16*   wsq    = (u16*)(ws + 2097152ull);       //  67,108,864 B
    u16*   xb     = (u16*)(ws + 69206016ull);      //  67,108,864 B (P reuses this)
    u16*   P      = xb;                            //   8,388,608 B (after gemm_qkv)
    float* kvglob = (float*)(ws + 136314880ull);   //   2,621,440 B
    u16*   ksum   = (u16*)(ws + 138936320ull);     //      65,536 B -> 139,001,856

    // 0) x -> bf16, weights -> bf16 (W_qkv row-permuted), zero kv accumulator
    convert_all<<<17216, 256, 0, stream>>>(x, Wqkv, Wout, xb, wq_bf, wo_bf, kvglob);
    // 1) fused qkv GEMM: q' -> wsq ; per-head kv outer-product -> kvglob
    gemm_qkv<<<dim3(12, 512), 512, 0, stream>>>(xb, wq_bf, wsq, kvglob);
    // 2) P_b = kv_h @ Wout_h (per bh) ; extract ksum  (xb dead -> P reuses it)
    make_P<<<128, 256, 0, stream>>>(kvglob, wo_bf, P, ksum);
    // 3) out = sum_h z_h .* (q' @ P_b^T)_h + b_out  (z fused in-GEMM, fp32)
    gemm_final<<<dim3(4, 512), 512, 0, stream>>>(wsq, P, out, bout, ksum);
}